// Round 8
// baseline (844.425 us; speedup 1.0000x reference)
//
#include <hip/hip_runtime.h>
#include <hip/hip_bf16.h>
#include <cstdint>
#include <cstddef>

// ---------- helpers ----------
__device__ __forceinline__ float bf2f(unsigned short u) {
    return __uint_as_float(((unsigned int)u) << 16);
}
__device__ __forceinline__ unsigned short f2bf(float f) {
    unsigned int u = __float_as_uint(f);
    unsigned int r = (u + 0x7fff + ((u >> 16) & 1)) >> 16;
    return (unsigned short)r;
}

using bf16x8 = __attribute__((ext_vector_type(8))) short;
using f32x4  = __attribute__((ext_vector_type(4))) float;

// ---------- bucketed CSR build ----------
#define BKT_SHIFT 9
#define BKT_NODES 512
#define BKT_CAP   18432
#define BIN_TILE  4096

__global__ __launch_bounds__(256) void bin_kernel(const int* __restrict__ eidx, int E,
                                                  int nb, int ntiles,
                                                  int* __restrict__ gcur,
                                                  uint2* __restrict__ binned) {
    __shared__ int cnt[256];
    __shared__ int base[256];
    const int tid = threadIdx.x;
    for (int t = blockIdx.x; t < ntiles; t += gridDim.x) {
        cnt[tid] = 0;
        __syncthreads();
        int s[16], d[16];
        unsigned pk[16];  // (b << 16) | rank ; 0xFFFFFFFF = invalid
        #pragma unroll
        for (int j = 0; j < 16; ++j) {
            int e = t * BIN_TILE + j * 256 + tid;
            if (e < E) {
                s[j] = eidx[e];
                d[j] = eidx[E + e];
                int b = d[j] >> BKT_SHIFT;
                int r = atomicAdd(&cnt[b], 1);
                pk[j] = ((unsigned)b << 16) | (unsigned)r;
            } else {
                pk[j] = 0xFFFFFFFFu;
            }
        }
        __syncthreads();
        if (tid < nb) {
            int c = cnt[tid];
            base[tid] = c ? atomicAdd(&gcur[tid], c) : 0;
        }
        __syncthreads();
        #pragma unroll
        for (int j = 0; j < 16; ++j) {
            if (pk[j] != 0xFFFFFFFFu) {
                int b = (int)(pk[j] >> 16);
                int pos = base[b] + (int)(pk[j] & 0xFFFFu);
                if (pos < BKT_CAP)
                    binned[(size_t)b * BKT_CAP + pos] = make_uint2((unsigned)s[j], (unsigned)d[j]);
            }
        }
        __syncthreads();
    }
}

__global__ __launch_bounds__(256) void bucket_scan_kernel(const int* __restrict__ gcur,
                                                          int* __restrict__ gbase,
                                                          int* __restrict__ rowptr, int nb, int n) {
    __shared__ int wsum[4];
    int tid = threadIdx.x, lane = tid & 63, wave = tid >> 6;
    int c = (tid < nb) ? min(gcur[tid], BKT_CAP) : 0;
    int inc = c;
    #pragma unroll
    for (int off = 1; off < 64; off <<= 1) {
        int t = __shfl_up(inc, off, 64);
        if (lane >= off) inc += t;
    }
    if (lane == 63) wsum[wave] = inc;
    __syncthreads();
    int wbase = 0;
    #pragma unroll
    for (int w = 0; w < 4; ++w)
        if (w < wave) wbase += wsum[w];
    int excl = wbase + inc - c;
    if (tid < nb) gbase[tid] = excl;
    if (tid == nb - 1) rowptr[n] = excl + c;
}

__global__ __launch_bounds__(256) void bhist_scan_kernel(const uint2* __restrict__ binned,
                                                         const int* __restrict__ gcur,
                                                         const int* __restrict__ gbase,
                                                         int* __restrict__ rowptr,
                                                         float* __restrict__ dinv, int n) {
    __shared__ int cnt[BKT_NODES];
    __shared__ int wsum[4];
    int b = blockIdx.x;
    int base_node = b << BKT_SHIFT;
    int tid = threadIdx.x, lane = tid & 63, wave = tid >> 6;
    for (int i = tid; i < BKT_NODES; i += 256) cnt[i] = 0;
    __syncthreads();
    int m = min(gcur[b], BKT_CAP);
    const uint2* eb = binned + (size_t)b * BKT_CAP;
    for (int i = tid; i < m; i += 256) {
        int idx = (int)eb[i].y - base_node;
        if (idx >= 0 && idx < BKT_NODES) atomicAdd(&cnt[idx], 1);
    }
    __syncthreads();
    int c0 = cnt[2 * tid], c1 = cnt[2 * tid + 1];
    int s = c0 + c1;
    int inc = s;
    #pragma unroll
    for (int off = 1; off < 64; off <<= 1) {
        int t = __shfl_up(inc, off, 64);
        if (lane >= off) inc += t;
    }
    if (lane == 63) wsum[wave] = inc;
    __syncthreads();
    int wbase = 0;
    #pragma unroll
    for (int w = 0; w < 4; ++w)
        if (w < wave) wbase += wsum[w];
    int excl = wbase + inc - s;
    int gb = gbase[b];
    int node0 = base_node + 2 * tid;
    if (node0 < n) {
        rowptr[node0] = gb + excl;
        dinv[node0] = rsqrtf((float)c0 + 1.0f);
    }
    if (node0 + 1 < n) {
        rowptr[node0 + 1] = gb + excl + c0;
        dinv[node0 + 1] = rsqrtf((float)c1 + 1.0f);
    }
}

__global__ __launch_bounds__(256) void lfill_kernel(const uint2* __restrict__ binned,
                                                    const int* __restrict__ gcur,
                                                    const int* __restrict__ rowptr,
                                                    int* __restrict__ csr_src, int n) {
    __shared__ int cur[BKT_NODES];
    int b = blockIdx.x;
    int base_node = b << BKT_SHIFT;
    for (int i = threadIdx.x; i < BKT_NODES; i += 256) {
        int node = base_node + i;
        cur[i] = (node < n) ? rowptr[node] : 0;
    }
    __syncthreads();
    int m = min(gcur[b], BKT_CAP);
    const uint2* eb = binned + (size_t)b * BKT_CAP;
    for (int i = threadIdx.x; i < m; i += 256) {
        uint2 p = eb[i];
        int idx = (int)p.y - base_node;
        if (idx >= 0 && idx < BKT_NODES) {
            int pos = atomicAdd(&cur[idx], 1);
            csr_src[pos] = (int)p.x;
        }
    }
}

// ---------- fallback CSR build ----------
__global__ __launch_bounds__(256) void hist_kernel(const int* __restrict__ dst, int E,
                                                   int* __restrict__ deg) {
    int i = blockIdx.x * blockDim.x + threadIdx.x;
    int stride = gridDim.x * blockDim.x;
    for (int e = i; e < E; e += stride) atomicAdd(&deg[dst[e]], 1);
}

__global__ __launch_bounds__(256) void fill_kernel(const int* __restrict__ eidx, int E,
                                                   int* __restrict__ cursor,
                                                   int* __restrict__ csr_src) {
    int e = blockIdx.x * blockDim.x + threadIdx.x;
    if (e < E) {
        int s = eidx[e];
        int d = eidx[E + e];
        int pos = atomicAdd(&cursor[d], 1);
        csr_src[pos] = s;
    }
}

__global__ __launch_bounds__(256) void scan_kernel(const int* __restrict__ deg,
                                                   int* __restrict__ rowptr, int n) {
    __shared__ int wsum[4];
    __shared__ int carry_s;
    int tid = threadIdx.x, lane = tid & 63, wave = tid >> 6;
    if (tid == 0) carry_s = 0;
    __syncthreads();
    const int CHUNK = 16;
    const int PER_ITER = 256 * CHUNK;
    for (int base = 0; base < n; base += PER_ITER) {
        int idx0 = base + tid * CHUNK;
        int v[CHUNK];
        int s = 0;
        #pragma unroll
        for (int j = 0; j < CHUNK; ++j) {
            int i = idx0 + j;
            v[j] = (i < n) ? deg[i] : 0;
            s += v[j];
        }
        int inc = s;
        #pragma unroll
        for (int off = 1; off < 64; off <<= 1) {
            int t = __shfl_up(inc, off, 64);
            if (lane >= off) inc += t;
        }
        if (lane == 63) wsum[wave] = inc;
        __syncthreads();
        int wbase = 0;
        #pragma unroll
        for (int w = 0; w < 4; ++w)
            if (w < wave) wbase += wsum[w];
        int total_iter = wsum[0] + wsum[1] + wsum[2] + wsum[3];
        int carry = carry_s;
        __syncthreads();
        if (tid == 0) carry_s = carry + total_iter;
        int run = carry + wbase + (inc - s);
        #pragma unroll
        for (int j = 0; j < CHUNK; ++j) {
            int i = idx0 + j;
            if (i < n) rowptr[i] = run;
            run += v[j];
        }
        __syncthreads();
    }
    if (tid == 0) rowptr[n] = carry_s;
}

__global__ __launch_bounds__(256) void dinv_kernel(const int* __restrict__ deg,
                                                   float* __restrict__ dinv, int n) {
    int i = blockIdx.x * blockDim.x + threadIdx.x;
    if (i < n) dinv[i] = rsqrtf((float)deg[i] + 1.0f);
}

// ---------- weight transpose+convert (both layers in one launch) ----------
// W1 [512,256] -> W1T [256,512] bf16 ; W2 [256,128] -> W2T [128,256] bf16
__global__ __launch_bounds__(256) void wt_kernel(const float* __restrict__ W1,
                                                 const float* __restrict__ W2,
                                                 unsigned short* __restrict__ W1T,
                                                 unsigned short* __restrict__ W2T) {
    int i = blockIdx.x * 256 + threadIdx.x;
    const int n1 = 512 * 256;
    if (i < n1) {
        int nn = i / 512, kk = i % 512;
        W1T[i] = f2bf(W1[(size_t)kk * 256 + nn]);
    } else {
        int j = i - n1;
        if (j < 256 * 128) {
            int nn = j / 256, kk = j % 256;
            W2T[j] = f2bf(W2[(size_t)kk * 128 + nn]);
        }
    }
}

// ---------- A-tile LDS staging loaders ----------
__device__ __forceinline__ bf16x8 load8_as_bf16(const float* p) {
    float4 lo = *reinterpret_cast<const float4*>(p);
    float4 hi = *reinterpret_cast<const float4*>(p + 4);
    bf16x8 r;
    r[0] = (short)f2bf(lo.x); r[1] = (short)f2bf(lo.y);
    r[2] = (short)f2bf(lo.z); r[3] = (short)f2bf(lo.w);
    r[4] = (short)f2bf(hi.x); r[5] = (short)f2bf(hi.y);
    r[6] = (short)f2bf(hi.z); r[7] = (short)f2bf(hi.w);
    return r;
}
__device__ __forceinline__ bf16x8 load8_as_bf16(const unsigned short* p) {
    return *reinterpret_cast<const bf16x8*>(p);
}

// ---------- MFMA GEMM: C[M, NT*64](bf16, scaled by dinv[row]) = A[M,K] * BT[N,K]^T ----------
template <typename AT, int NT>
__global__ __launch_bounds__(256) void gemm_mfma(const AT* __restrict__ A,
                                                 const unsigned short* __restrict__ BT,
                                                 const float* __restrict__ dinv,
                                                 unsigned short* __restrict__ C,
                                                 int M, int N, int K) {
    constexpr int LP = 40;  // padded LDS row stride (shorts)
    __shared__ short As[64 * LP];
    __shared__ short Bs[NT * 64 * LP];
    const int tid = threadIdx.x;
    const int wave = tid >> 6, lane = tid & 63;
    const int quad = lane >> 4, l16 = lane & 15;
    const int m0 = blockIdx.x * 64;
    const int srow = tid >> 2, sseg = (tid & 3) * 8;
    const int arow = m0 + srow;
    f32x4 acc[NT][4] = {};

    for (int k0 = 0; k0 < K; k0 += 32) {
        bf16x8 av = {};
        if (arow < M) av = load8_as_bf16(A + (size_t)arow * K + k0 + sseg);
        *reinterpret_cast<bf16x8*>(&As[srow * LP + sseg]) = av;
        #pragma unroll
        for (int i = 0; i < NT; ++i) {
            bf16x8 bv = load8_as_bf16(BT + (size_t)(i * 64 + srow) * K + k0 + sseg);
            *reinterpret_cast<bf16x8*>(&Bs[(i * 64 + srow) * LP + sseg]) = bv;
        }
        __syncthreads();
        bf16x8 af = *reinterpret_cast<bf16x8*>(&As[(wave * 16 + l16) * LP + quad * 8]);
        #pragma unroll
        for (int i = 0; i < NT; ++i) {
            #pragma unroll
            for (int ct = 0; ct < 4; ++ct) {
                bf16x8 bfr =
                    *reinterpret_cast<bf16x8*>(&Bs[(i * 64 + ct * 16 + l16) * LP + quad * 8]);
                acc[i][ct] = __builtin_amdgcn_mfma_f32_16x16x32_bf16(af, bfr, acc[i][ct], 0, 0, 0);
            }
        }
        __syncthreads();
    }
    #pragma unroll
    for (int r = 0; r < 4; ++r) {
        int row = m0 + wave * 16 + quad * 4 + r;
        if (row < M) {
            float dv = dinv[row];
            #pragma unroll
            for (int i = 0; i < NT; ++i)
                #pragma unroll
                for (int ct = 0; ct < 4; ++ct)
                    C[(size_t)row * N + i * 64 + ct * 16 + l16] = f2bf(acc[i][ct][r] * dv);
        }
    }
}

// ---------- agg layer 1: h1 = relu(dinv*(sum+self)+b1), H=256 (32 lanes x 8) ----------
__global__ __launch_bounds__(256) void agg1_kernel(const unsigned short* __restrict__ hs,
                                                   const float* __restrict__ dinv,
                                                   const int* __restrict__ rowptr,
                                                   const int* __restrict__ csr_src,
                                                   const float* __restrict__ bias,
                                                   unsigned short* __restrict__ hout, int n) {
    constexpr int LANES = 32, H = 256, NPB = 8;
    int sub = threadIdx.x / LANES;
    int lane = threadIdx.x % LANES;
    int node = blockIdx.x * NPB + sub;
    if (node >= n) return;
    const unsigned short* tab = hs + (size_t)lane * 8;
    float a[8];
    bf16x8 v0 = *reinterpret_cast<const bf16x8*>(tab + (size_t)node * H);
    #pragma unroll
    for (int j = 0; j < 8; ++j) a[j] = bf2f((unsigned short)v0[j]);
    int e0 = rowptr[node], e1 = rowptr[node + 1];
    int p = e0;
    for (; p + 8 <= e1; p += 8) {
        int s[8];
        #pragma unroll
        for (int u = 0; u < 8; ++u) s[u] = csr_src[p + u];
        bf16x8 w[8];
        #pragma unroll
        for (int u = 0; u < 8; ++u)
            w[u] = *reinterpret_cast<const bf16x8*>(tab + (size_t)s[u] * H);
        #pragma unroll
        for (int u = 0; u < 8; ++u)
            #pragma unroll
            for (int j = 0; j < 8; ++j) a[j] += bf2f((unsigned short)w[u][j]);
    }
    for (; p < e1; ++p) {
        int s = csr_src[p];
        bf16x8 w = *reinterpret_cast<const bf16x8*>(tab + (size_t)s * H);
        #pragma unroll
        for (int j = 0; j < 8; ++j) a[j] += bf2f((unsigned short)w[j]);
    }
    float dv = dinv[node];
    float4 blo = *(reinterpret_cast<const float4*>(bias) + lane * 2);
    float4 bhi = *(reinterpret_cast<const float4*>(bias) + lane * 2 + 1);
    float bvals[8] = {blo.x, blo.y, blo.z, blo.w, bhi.x, bhi.y, bhi.z, bhi.w};
    bf16x8 o;
    #pragma unroll
    for (int j = 0; j < 8; ++j)
        o[j] = (short)f2bf(fmaxf(fmaf(a[j], dv, bvals[j]), 0.f));
    // h1 is streamed once by gemm2 -> keep it out of L2 (preserve gather lines)
    __builtin_nontemporal_store(o, reinterpret_cast<bf16x8*>(hout + (size_t)node * H + lane * 8));
}

// ---------- agg layer 2 + fused head: out = log_softmax(relu(agg)@Wl + bl) ----------
// H=128: 16 lanes x 8 feats. h2 never touches memory.
__global__ __launch_bounds__(256) void agg2_head_kernel(const unsigned short* __restrict__ hs,
                                                        const float* __restrict__ dinv,
                                                        const int* __restrict__ rowptr,
                                                        const int* __restrict__ csr_src,
                                                        const float* __restrict__ bias,
                                                        const float* __restrict__ Wl,
                                                        const float* __restrict__ bl,
                                                        float* __restrict__ out, int n) {
    constexpr int LANES = 16, H = 128, NPB = 16;
    int sub = threadIdx.x / LANES;
    int lane = threadIdx.x % LANES;
    int node = blockIdx.x * NPB + sub;
    if (node >= n) return;
    const unsigned short* tab = hs + (size_t)lane * 8;
    float a[8];
    bf16x8 v0 = *reinterpret_cast<const bf16x8*>(tab + (size_t)node * H);
    #pragma unroll
    for (int j = 0; j < 8; ++j) a[j] = bf2f((unsigned short)v0[j]);
    int e0 = rowptr[node], e1 = rowptr[node + 1];
    int p = e0;
    for (; p + 8 <= e1; p += 8) {
        int s[8];
        #pragma unroll
        for (int u = 0; u < 8; ++u) s[u] = csr_src[p + u];
        bf16x8 w[8];
        #pragma unroll
        for (int u = 0; u < 8; ++u)
            w[u] = *reinterpret_cast<const bf16x8*>(tab + (size_t)s[u] * H);
        #pragma unroll
        for (int u = 0; u < 8; ++u)
            #pragma unroll
            for (int j = 0; j < 8; ++j) a[j] += bf2f((unsigned short)w[u][j]);
    }
    for (; p < e1; ++p) {
        int s = csr_src[p];
        bf16x8 w = *reinterpret_cast<const bf16x8*>(tab + (size_t)s * H);
        #pragma unroll
        for (int j = 0; j < 8; ++j) a[j] += bf2f((unsigned short)w[j]);
    }
    float dv = dinv[node];
    float4 blo = *(reinterpret_cast<const float4*>(bias) + lane * 2);
    float4 bhi = *(reinterpret_cast<const float4*>(bias) + lane * 2 + 1);
    float bvals[8] = {blo.x, blo.y, blo.z, blo.w, bhi.x, bhi.y, bhi.z, bhi.w};
    float h[8];
    #pragma unroll
    for (int j = 0; j < 8; ++j)
        h[j] = fmaxf(fmaf(a[j], dv, bvals[j]), 0.f);
    // head partials: this lane covers features lane*8..lane*8+7
    float p0 = 0.f, p1 = 0.f, p2 = 0.f, p3 = 0.f;
    #pragma unroll
    for (int j = 0; j < 8; ++j) {
        float4 w = *reinterpret_cast<const float4*>(Wl + (size_t)(lane * 8 + j) * 4);
        p0 = fmaf(h[j], w.x, p0); p1 = fmaf(h[j], w.y, p1);
        p2 = fmaf(h[j], w.z, p2); p3 = fmaf(h[j], w.w, p3);
    }
    // reduce across the node's 16 lanes
    #pragma unroll
    for (int m = 1; m < 16; m <<= 1) {
        p0 += __shfl_xor(p0, m, 16);
        p1 += __shfl_xor(p1, m, 16);
        p2 += __shfl_xor(p2, m, 16);
        p3 += __shfl_xor(p3, m, 16);
    }
    if (lane == 0) {
        p0 += bl[0]; p1 += bl[1]; p2 += bl[2]; p3 += bl[3];
        float mx = fmaxf(fmaxf(p0, p1), fmaxf(p2, p3));
        float s = __expf(p0 - mx) + __expf(p1 - mx) + __expf(p2 - mx) + __expf(p3 - mx);
        float lse = mx + __logf(s);
        *(reinterpret_cast<float4*>(out) + node) = make_float4(p0 - lse, p1 - lse, p2 - lse, p3 - lse);
    }
}

// ---------- launch ----------
extern "C" void kernel_launch(void* const* d_in, const int* in_sizes, int n_in,
                              void* d_out, int out_size, void* d_ws, size_t ws_size,
                              hipStream_t stream) {
    const float* x  = (const float*)d_in[0];
    const int* eidx = (const int*)d_in[1];
    const float* W1 = (const float*)d_in[2];
    const float* b1 = (const float*)d_in[3];
    const float* W2 = (const float*)d_in[4];
    const float* b2 = (const float*)d_in[5];
    const float* Wl = (const float*)d_in[6];
    const float* bl = (const float*)d_in[7];
    float* out = (float*)d_out;

    const int n = in_sizes[0] / 512;
    const int E = in_sizes[1] / 2;
    const int nb = (n + BKT_NODES - 1) >> BKT_SHIFT;  // 196 for n=100000

    char* ws = (char*)d_ws;
    size_t off = 0;
    auto alloc = [&](size_t bytes) -> void* {
        void* p = ws + off;
        off += (bytes + 255) & ~(size_t)255;
        return p;
    };
    unsigned short* hA  = (unsigned short*)alloc((size_t)n * 256 * 2);
    unsigned short* hB  = (unsigned short*)alloc((size_t)n * 256 * 2);
    unsigned short* W1T = (unsigned short*)alloc((size_t)256 * 512 * 2);
    unsigned short* W2T = (unsigned short*)alloc((size_t)128 * 256 * 2);
    int* deg     = (int*)alloc((size_t)n * 4);
    int* rowptr  = (int*)alloc(((size_t)n + 1) * 4);
    int* cursor  = (int*)alloc((size_t)n * 4);
    float* dinv  = (float*)alloc((size_t)n * 4);
    int* csr_src = (int*)alloc((size_t)E * 4);
    int* gcur    = (int*)alloc((size_t)nb * 4);
    int* gbase   = (int*)alloc((size_t)nb * 4);
    size_t need_binned = off + (size_t)nb * BKT_CAP * 8 + 256;
    uint2* binned = (uint2*)alloc((size_t)nb * BKT_CAP * 8);

    if (need_binned <= ws_size && nb <= 256) {
        hipMemsetAsync(gcur, 0, (size_t)nb * 4, stream);
        int ntiles = (E + BIN_TILE - 1) / BIN_TILE;
        bin_kernel<<<dim3(256), dim3(256), 0, stream>>>(eidx, E, nb, ntiles, gcur, binned);
        bucket_scan_kernel<<<dim3(1), dim3(256), 0, stream>>>(gcur, gbase, rowptr, nb, n);
        bhist_scan_kernel<<<dim3(nb), dim3(256), 0, stream>>>(binned, gcur, gbase, rowptr, dinv, n);
        lfill_kernel<<<dim3(nb), dim3(256), 0, stream>>>(binned, gcur, rowptr, csr_src, n);
    } else {
        hipMemsetAsync(deg, 0, (size_t)n * 4, stream);
        hist_kernel<<<dim3(1024), dim3(256), 0, stream>>>(eidx + E, E, deg);
        scan_kernel<<<dim3(1), dim3(256), 0, stream>>>(deg, rowptr, n);
        dinv_kernel<<<dim3((n + 255) / 256), dim3(256), 0, stream>>>(deg, dinv, n);
        hipMemcpyAsync(cursor, rowptr, (size_t)n * 4, hipMemcpyDeviceToDevice, stream);
        fill_kernel<<<dim3((E + 255) / 256), dim3(256), 0, stream>>>(eidx, E, cursor, csr_src);
    }

    // Weight prep (single launch, both layers)
    wt_kernel<<<dim3((512 * 256 + 256 * 128 + 255) / 256), dim3(256), 0, stream>>>(
        W1, W2, W1T, W2T);

    const int mblocks = (n + 63) / 64;

    // Layer 1: hs1 = (x@W1)*dinv -> agg1 -> h1 (nt-stored)
    gemm_mfma<float, 4><<<dim3(mblocks), dim3(256), 0, stream>>>(
        x, W1T, dinv, hA, n, 256, 512);
    agg1_kernel<<<dim3((n + 7) / 8), dim3(256), 0, stream>>>(
        hA, dinv, rowptr, csr_src, b1, hB, n);

    // Layer 2: hs2 = (h1@W2)*dinv -> agg2+head fused -> out
    gemm_mfma<unsigned short, 2><<<dim3(mblocks), dim3(256), 0, stream>>>(
        hB, W2T, dinv, hA, n, 128, 256);
    agg2_head_kernel<<<dim3((n + 15) / 16), dim3(256), 0, stream>>>(
        hA, dinv, rowptr, csr_src, b2, Wl, bl, out, n);
}

// Round 9
// 843.653 us; speedup vs baseline: 1.0009x; 1.0009x over previous
//
#include <hip/hip_runtime.h>
#include <hip/hip_bf16.h>
#include <cstdint>
#include <cstddef>

// ---------- helpers ----------
__device__ __forceinline__ float bf2f(unsigned short u) {
    return __uint_as_float(((unsigned int)u) << 16);
}
__device__ __forceinline__ unsigned short f2bf(float f) {
    unsigned int u = __float_as_uint(f);
    unsigned int r = (u + 0x7fff + ((u >> 16) & 1)) >> 16;
    return (unsigned short)r;
}

using bf16x8 = __attribute__((ext_vector_type(8))) short;
using f32x4  = __attribute__((ext_vector_type(4))) float;

// ---------- bucketed CSR build ----------
#define BKT_SHIFT 9
#define BKT_NODES 512
#define BKT_CAP   18432
#define BIN_TILE  4096

// packed entry: (src << 9) | dst_local  (requires n < 2^23)
__global__ __launch_bounds__(256) void bin_kernel(const int* __restrict__ eidx, int E,
                                                  int nb, int ntiles,
                                                  int* __restrict__ gcur,
                                                  unsigned* __restrict__ binned) {
    __shared__ int cnt[256];
    __shared__ int base[256];
    const int tid = threadIdx.x;
    for (int t = blockIdx.x; t < ntiles; t += gridDim.x) {
        cnt[tid] = 0;
        __syncthreads();
        int s[16], d[16];
        unsigned pk[16];  // (b << 16) | rank ; 0xFFFFFFFF = invalid
        #pragma unroll
        for (int j = 0; j < 16; ++j) {
            int e = t * BIN_TILE + j * 256 + tid;
            if (e < E) {
                s[j] = eidx[e];
                d[j] = eidx[E + e];
                int b = d[j] >> BKT_SHIFT;
                int r = atomicAdd(&cnt[b], 1);
                pk[j] = ((unsigned)b << 16) | (unsigned)r;
            } else {
                pk[j] = 0xFFFFFFFFu;
            }
        }
        __syncthreads();
        if (tid < nb) {
            int c = cnt[tid];
            base[tid] = c ? atomicAdd(&gcur[tid], c) : 0;
        }
        __syncthreads();
        #pragma unroll
        for (int j = 0; j < 16; ++j) {
            if (pk[j] != 0xFFFFFFFFu) {
                int b = (int)(pk[j] >> 16);
                int pos = base[b] + (int)(pk[j] & 0xFFFFu);
                if (pos < BKT_CAP)
                    binned[(size_t)b * BKT_CAP + pos] =
                        ((unsigned)s[j] << BKT_SHIFT) | ((unsigned)d[j] & (BKT_NODES - 1));
            }
        }
        __syncthreads();
    }
}

// fused: bucket-base scan (redundant per block) + per-bucket histogram + local scan
//        -> rowptr, dinv, and csr_src fill via LDS cursors. One pass over binned.
__global__ __launch_bounds__(256) void csr_build_kernel(const unsigned* __restrict__ binned,
                                                        const int* __restrict__ gcur,
                                                        int* __restrict__ rowptr,
                                                        float* __restrict__ dinv,
                                                        int* __restrict__ csr_src,
                                                        int nb, int n) {
    __shared__ int cnt[BKT_NODES];
    __shared__ int sbase[256];
    __shared__ int wsum[4];
    const int b = blockIdx.x;
    const int base_node = b << BKT_SHIFT;
    const int tid = threadIdx.x, lane = tid & 63, wave = tid >> 6;

    // bucket-base exclusive scan over gcur (all blocks redundantly)
    int c = (tid < nb) ? min(gcur[tid], BKT_CAP) : 0;
    int inc = c;
    #pragma unroll
    for (int off = 1; off < 64; off <<= 1) {
        int t = __shfl_up(inc, off, 64);
        if (lane >= off) inc += t;
    }
    if (lane == 63) wsum[wave] = inc;
    __syncthreads();
    int wbase = 0;
    #pragma unroll
    for (int w = 0; w < 4; ++w)
        if (w < wave) wbase += wsum[w];
    sbase[tid] = wbase + inc - c;
    __syncthreads();
    const int gb = sbase[b];
    if (b == 0 && tid == 0)
        rowptr[n] = sbase[nb - 1] + min(gcur[nb - 1], BKT_CAP);
    __syncthreads();

    // per-bucket histogram
    for (int i = tid; i < BKT_NODES; i += 256) cnt[i] = 0;
    __syncthreads();
    const int m = min(gcur[b], BKT_CAP);
    const unsigned* eb = binned + (size_t)b * BKT_CAP;
    for (int i = tid; i < m; i += 256)
        atomicAdd(&cnt[eb[i] & (BKT_NODES - 1)], 1);
    __syncthreads();

    // local scan (2 elems/thread) -> rowptr, dinv, LDS cursors
    int c0 = cnt[2 * tid], c1 = cnt[2 * tid + 1];
    int s = c0 + c1;
    int inc2 = s;
    #pragma unroll
    for (int off = 1; off < 64; off <<= 1) {
        int t = __shfl_up(inc2, off, 64);
        if (lane >= off) inc2 += t;
    }
    __syncthreads();  // wsum reuse
    if (lane == 63) wsum[wave] = inc2;
    __syncthreads();
    int wbase2 = 0;
    #pragma unroll
    for (int w = 0; w < 4; ++w)
        if (w < wave) wbase2 += wsum[w];
    int excl = wbase2 + inc2 - s;
    int node0 = base_node + 2 * tid;
    if (node0 < n) {
        rowptr[node0] = gb + excl;
        dinv[node0] = rsqrtf((float)c0 + 1.0f);
    }
    if (node0 + 1 < n) {
        rowptr[node0 + 1] = gb + excl + c0;
        dinv[node0 + 1] = rsqrtf((float)c1 + 1.0f);
    }
    __syncthreads();
    cnt[2 * tid] = gb + excl;
    cnt[2 * tid + 1] = gb + excl + c0;
    __syncthreads();

    // fill
    for (int i = tid; i < m; i += 256) {
        unsigned p = eb[i];
        int pos = atomicAdd(&cnt[p & (BKT_NODES - 1)], 1);
        csr_src[pos] = (int)(p >> BKT_SHIFT);
    }
}

// ---------- fallback CSR build ----------
__global__ __launch_bounds__(256) void hist_kernel(const int* __restrict__ dst, int E,
                                                   int* __restrict__ deg) {
    int i = blockIdx.x * blockDim.x + threadIdx.x;
    int stride = gridDim.x * blockDim.x;
    for (int e = i; e < E; e += stride) atomicAdd(&deg[dst[e]], 1);
}

__global__ __launch_bounds__(256) void fill_kernel(const int* __restrict__ eidx, int E,
                                                   int* __restrict__ cursor,
                                                   int* __restrict__ csr_src) {
    int e = blockIdx.x * blockDim.x + threadIdx.x;
    if (e < E) {
        int s = eidx[e];
        int d = eidx[E + e];
        int pos = atomicAdd(&cursor[d], 1);
        csr_src[pos] = s;
    }
}

__global__ __launch_bounds__(256) void scan_kernel(const int* __restrict__ deg,
                                                   int* __restrict__ rowptr, int n) {
    __shared__ int wsum[4];
    __shared__ int carry_s;
    int tid = threadIdx.x, lane = tid & 63, wave = tid >> 6;
    if (tid == 0) carry_s = 0;
    __syncthreads();
    const int CHUNK = 16;
    const int PER_ITER = 256 * CHUNK;
    for (int base = 0; base < n; base += PER_ITER) {
        int idx0 = base + tid * CHUNK;
        int v[CHUNK];
        int s = 0;
        #pragma unroll
        for (int j = 0; j < CHUNK; ++j) {
            int i = idx0 + j;
            v[j] = (i < n) ? deg[i] : 0;
            s += v[j];
        }
        int inc = s;
        #pragma unroll
        for (int off = 1; off < 64; off <<= 1) {
            int t = __shfl_up(inc, off, 64);
            if (lane >= off) inc += t;
        }
        if (lane == 63) wsum[wave] = inc;
        __syncthreads();
        int wbase = 0;
        #pragma unroll
        for (int w = 0; w < 4; ++w)
            if (w < wave) wbase += wsum[w];
        int total_iter = wsum[0] + wsum[1] + wsum[2] + wsum[3];
        int carry = carry_s;
        __syncthreads();
        if (tid == 0) carry_s = carry + total_iter;
        int run = carry + wbase + (inc - s);
        #pragma unroll
        for (int j = 0; j < CHUNK; ++j) {
            int i = idx0 + j;
            if (i < n) rowptr[i] = run;
            run += v[j];
        }
        __syncthreads();
    }
    if (tid == 0) rowptr[n] = carry_s;
}

__global__ __launch_bounds__(256) void dinv_kernel(const int* __restrict__ deg,
                                                   float* __restrict__ dinv, int n) {
    int i = blockIdx.x * blockDim.x + threadIdx.x;
    if (i < n) dinv[i] = rsqrtf((float)deg[i] + 1.0f);
}

// ---------- weight transpose+convert (both layers, one launch) ----------
__global__ __launch_bounds__(256) void wt_kernel(const float* __restrict__ W1,
                                                 const float* __restrict__ W2,
                                                 unsigned short* __restrict__ W1T,
                                                 unsigned short* __restrict__ W2T) {
    int i = blockIdx.x * 256 + threadIdx.x;
    const int n1 = 512 * 256;
    if (i < n1) {
        int nn = i / 512, kk = i % 512;
        W1T[i] = f2bf(W1[(size_t)kk * 256 + nn]);
    } else {
        int j = i - n1;
        if (j < 256 * 128) {
            int nn = j / 256, kk = j % 256;
            W2T[j] = f2bf(W2[(size_t)kk * 128 + nn]);
        }
    }
}

// ---------- A-tile LDS staging loaders ----------
__device__ __forceinline__ bf16x8 load8_as_bf16(const float* p) {
    float4 lo = *reinterpret_cast<const float4*>(p);
    float4 hi = *reinterpret_cast<const float4*>(p + 4);
    bf16x8 r;
    r[0] = (short)f2bf(lo.x); r[1] = (short)f2bf(lo.y);
    r[2] = (short)f2bf(lo.z); r[3] = (short)f2bf(lo.w);
    r[4] = (short)f2bf(hi.x); r[5] = (short)f2bf(hi.y);
    r[6] = (short)f2bf(hi.z); r[7] = (short)f2bf(hi.w);
    return r;
}

// ---------- MFMA GEMM1: C[M, 256](bf16, scaled by dinv[row]) = A[M,512] * W1T^T ----------
template <typename AT, int NT>
__global__ __launch_bounds__(256) void gemm_mfma(const AT* __restrict__ A,
                                                 const unsigned short* __restrict__ BT,
                                                 const float* __restrict__ dinv,
                                                 unsigned short* __restrict__ C,
                                                 int M, int N, int K) {
    constexpr int LP = 40;
    __shared__ short As[64 * LP];
    __shared__ short Bs[NT * 64 * LP];
    const int tid = threadIdx.x;
    const int wave = tid >> 6, lane = tid & 63;
    const int quad = lane >> 4, l16 = lane & 15;
    const int m0 = blockIdx.x * 64;
    const int srow = tid >> 2, sseg = (tid & 3) * 8;
    const int arow = m0 + srow;
    f32x4 acc[NT][4] = {};

    for (int k0 = 0; k0 < K; k0 += 32) {
        bf16x8 av = {};
        if (arow < M) av = load8_as_bf16(A + (size_t)arow * K + k0 + sseg);
        *reinterpret_cast<bf16x8*>(&As[srow * LP + sseg]) = av;
        #pragma unroll
        for (int i = 0; i < NT; ++i) {
            bf16x8 bv = *reinterpret_cast<const bf16x8*>(BT + (size_t)(i * 64 + srow) * K + k0 + sseg);
            *reinterpret_cast<bf16x8*>(&Bs[(i * 64 + srow) * LP + sseg]) = bv;
        }
        __syncthreads();
        bf16x8 af = *reinterpret_cast<bf16x8*>(&As[(wave * 16 + l16) * LP + quad * 8]);
        #pragma unroll
        for (int i = 0; i < NT; ++i) {
            #pragma unroll
            for (int ct = 0; ct < 4; ++ct) {
                bf16x8 bfr =
                    *reinterpret_cast<bf16x8*>(&Bs[(i * 64 + ct * 16 + l16) * LP + quad * 8]);
                acc[i][ct] = __builtin_amdgcn_mfma_f32_16x16x32_bf16(af, bfr, acc[i][ct], 0, 0, 0);
            }
        }
        __syncthreads();
    }
    #pragma unroll
    for (int r = 0; r < 4; ++r) {
        int row = m0 + wave * 16 + quad * 4 + r;
        if (row < M) {
            float dv = dinv[row];
            #pragma unroll
            for (int i = 0; i < NT; ++i)
                #pragma unroll
                for (int ct = 0; ct < 4; ++ct)
                    C[(size_t)row * N + i * 64 + ct * 16 + l16] = f2bf(acc[i][ct][r] * dv);
        }
    }
}

// ---------- fused agg1 + gemm2 ----------
// Phase 1: gather/aggregate h1 = relu(dinv*(sum+self)+b1) for 64 dst rows -> LDS A-tile.
// Phase 2: hs2[64 x 128] = (h1 @ W2T^T) * dinv  (h1 never touches global memory).
__global__ __launch_bounds__(256) void agg1_gemm2_kernel(const unsigned short* __restrict__ hs1,
                                                         const float* __restrict__ dinv,
                                                         const int* __restrict__ rowptr,
                                                         const int* __restrict__ csr_src,
                                                         const float* __restrict__ b1,
                                                         const unsigned short* __restrict__ W2T,
                                                         unsigned short* __restrict__ hs2,
                                                         int n) {
    constexpr int LPA = 264;  // 256 + 8 shorts pad
    constexpr int LPB = 40;
    __shared__ short As2[64 * LPA];   // 33.8 KB
    __shared__ short Bs[128 * LPB];   // 10.2 KB
    const int tid = threadIdx.x;
    const int m0 = blockIdx.x * 64;

    // ---- phase 1: gather (32 lanes/node, 8 feats/lane) ----
    {
        const int lane = tid & 31;
        const int sub = tid >> 5;  // 0..7
        const unsigned short* tab = hs1 + (size_t)lane * 8;
        float4 blo = *(reinterpret_cast<const float4*>(b1) + lane * 2);
        float4 bhi = *(reinterpret_cast<const float4*>(b1) + lane * 2 + 1);
        float bvals[8] = {blo.x, blo.y, blo.z, blo.w, bhi.x, bhi.y, bhi.z, bhi.w};
        for (int g = 0; g < 8; ++g) {
            int row = g * 8 + sub;
            int node = m0 + row;
            float h[8] = {};
            if (node < n) {
                float a[8];
                bf16x8 v0 = *reinterpret_cast<const bf16x8*>(tab + (size_t)node * 256);
                #pragma unroll
                for (int j = 0; j < 8; ++j) a[j] = bf2f((unsigned short)v0[j]);
                int e0 = rowptr[node], e1 = rowptr[node + 1];
                int p = e0;
                for (; p + 8 <= e1; p += 8) {
                    int s[8];
                    #pragma unroll
                    for (int u = 0; u < 8; ++u) s[u] = csr_src[p + u];
                    bf16x8 w[8];
                    #pragma unroll
                    for (int u = 0; u < 8; ++u)
                        w[u] = *reinterpret_cast<const bf16x8*>(tab + (size_t)s[u] * 256);
                    #pragma unroll
                    for (int u = 0; u < 8; ++u)
                        #pragma unroll
                        for (int j = 0; j < 8; ++j) a[j] += bf2f((unsigned short)w[u][j]);
                }
                for (; p < e1; ++p) {
                    int s = csr_src[p];
                    bf16x8 w = *reinterpret_cast<const bf16x8*>(tab + (size_t)s * 256);
                    #pragma unroll
                    for (int j = 0; j < 8; ++j) a[j] += bf2f((unsigned short)w[j]);
                }
                float dv = dinv[node];
                #pragma unroll
                for (int j = 0; j < 8; ++j)
                    h[j] = fmaxf(fmaf(a[j], dv, bvals[j]), 0.f);
            }
            bf16x8 o;
            #pragma unroll
            for (int j = 0; j < 8; ++j) o[j] = (short)f2bf(h[j]);
            *reinterpret_cast<bf16x8*>(&As2[row * LPA + lane * 8]) = o;
        }
    }
    __syncthreads();

    // ---- phase 2: MFMA K=256, N=128 (NT=2) ----
    const int wave = tid >> 6, lane = tid & 63;
    const int quad = lane >> 4, l16 = lane & 15;
    const int srow = tid >> 2, sseg = (tid & 3) * 8;
    f32x4 acc[2][4] = {};
    for (int k0 = 0; k0 < 256; k0 += 32) {
        #pragma unroll
        for (int i = 0; i < 2; ++i) {
            bf16x8 bv =
                *reinterpret_cast<const bf16x8*>(W2T + (size_t)(i * 64 + srow) * 256 + k0 + sseg);
            *reinterpret_cast<bf16x8*>(&Bs[(i * 64 + srow) * LPB + sseg]) = bv;
        }
        __syncthreads();
        bf16x8 af = *reinterpret_cast<bf16x8*>(&As2[(wave * 16 + l16) * LPA + k0 + quad * 8]);
        #pragma unroll
        for (int i = 0; i < 2; ++i) {
            #pragma unroll
            for (int ct = 0; ct < 4; ++ct) {
                bf16x8 bfr =
                    *reinterpret_cast<bf16x8*>(&Bs[(i * 64 + ct * 16 + l16) * LPB + quad * 8]);
                acc[i][ct] = __builtin_amdgcn_mfma_f32_16x16x32_bf16(af, bfr, acc[i][ct], 0, 0, 0);
            }
        }
        __syncthreads();
    }
    #pragma unroll
    for (int r = 0; r < 4; ++r) {
        int row = m0 + wave * 16 + quad * 4 + r;
        if (row < n) {
            float dv = dinv[row];
            #pragma unroll
            for (int i = 0; i < 2; ++i)
                #pragma unroll
                for (int ct = 0; ct < 4; ++ct)
                    hs2[(size_t)row * 128 + i * 64 + ct * 16 + l16] = f2bf(acc[i][ct][r] * dv);
        }
    }
}

// ---------- agg layer 2 + fused head ----------
__global__ __launch_bounds__(256) void agg2_head_kernel(const unsigned short* __restrict__ hs,
                                                        const float* __restrict__ dinv,
                                                        const int* __restrict__ rowptr,
                                                        const int* __restrict__ csr_src,
                                                        const float* __restrict__ bias,
                                                        const float* __restrict__ Wl,
                                                        const float* __restrict__ bl,
                                                        float* __restrict__ out, int n) {
    constexpr int LANES = 16, H = 128, NPB = 16;
    int sub = threadIdx.x / LANES;
    int lane = threadIdx.x % LANES;
    int node = blockIdx.x * NPB + sub;
    if (node >= n) return;
    const unsigned short* tab = hs + (size_t)lane * 8;
    float a[8];
    bf16x8 v0 = *reinterpret_cast<const bf16x8*>(tab + (size_t)node * H);
    #pragma unroll
    for (int j = 0; j < 8; ++j) a[j] = bf2f((unsigned short)v0[j]);
    int e0 = rowptr[node], e1 = rowptr[node + 1];
    int p = e0;
    for (; p + 8 <= e1; p += 8) {
        int s[8];
        #pragma unroll
        for (int u = 0; u < 8; ++u) s[u] = csr_src[p + u];
        bf16x8 w[8];
        #pragma unroll
        for (int u = 0; u < 8; ++u)
            w[u] = *reinterpret_cast<const bf16x8*>(tab + (size_t)s[u] * H);
        #pragma unroll
        for (int u = 0; u < 8; ++u)
            #pragma unroll
            for (int j = 0; j < 8; ++j) a[j] += bf2f((unsigned short)w[u][j]);
    }
    for (; p < e1; ++p) {
        int s = csr_src[p];
        bf16x8 w = *reinterpret_cast<const bf16x8*>(tab + (size_t)s * H);
        #pragma unroll
        for (int j = 0; j < 8; ++j) a[j] += bf2f((unsigned short)w[j]);
    }
    float dv = dinv[node];
    float4 blo = *(reinterpret_cast<const float4*>(bias) + lane * 2);
    float4 bhi = *(reinterpret_cast<const float4*>(bias) + lane * 2 + 1);
    float bvals[8] = {blo.x, blo.y, blo.z, blo.w, bhi.x, bhi.y, bhi.z, bhi.w};
    float h[8];
    #pragma unroll
    for (int j = 0; j < 8; ++j)
        h[j] = fmaxf(fmaf(a[j], dv, bvals[j]), 0.f);
    float p0 = 0.f, p1 = 0.f, p2 = 0.f, p3 = 0.f;
    #pragma unroll
    for (int j = 0; j < 8; ++j) {
        float4 w = *reinterpret_cast<const float4*>(Wl + (size_t)(lane * 8 + j) * 4);
        p0 = fmaf(h[j], w.x, p0); p1 = fmaf(h[j], w.y, p1);
        p2 = fmaf(h[j], w.z, p2); p3 = fmaf(h[j], w.w, p3);
    }
    #pragma unroll
    for (int m = 1; m < 16; m <<= 1) {
        p0 += __shfl_xor(p0, m, 16);
        p1 += __shfl_xor(p1, m, 16);
        p2 += __shfl_xor(p2, m, 16);
        p3 += __shfl_xor(p3, m, 16);
    }
    if (lane == 0) {
        p0 += bl[0]; p1 += bl[1]; p2 += bl[2]; p3 += bl[3];
        float mx = fmaxf(fmaxf(p0, p1), fmaxf(p2, p3));
        float s = __expf(p0 - mx) + __expf(p1 - mx) + __expf(p2 - mx) + __expf(p3 - mx);
        float lse = mx + __logf(s);
        *(reinterpret_cast<float4*>(out) + node) = make_float4(p0 - lse, p1 - lse, p2 - lse, p3 - lse);
    }
}

// ---------- launch ----------
extern "C" void kernel_launch(void* const* d_in, const int* in_sizes, int n_in,
                              void* d_out, int out_size, void* d_ws, size_t ws_size,
                              hipStream_t stream) {
    const float* x  = (const float*)d_in[0];
    const int* eidx = (const int*)d_in[1];
    const float* W1 = (const float*)d_in[2];
    const float* b1 = (const float*)d_in[3];
    const float* W2 = (const float*)d_in[4];
    const float* b2 = (const float*)d_in[5];
    const float* Wl = (const float*)d_in[6];
    const float* bl = (const float*)d_in[7];
    float* out = (float*)d_out;

    const int n = in_sizes[0] / 512;
    const int E = in_sizes[1] / 2;
    const int nb = (n + BKT_NODES - 1) >> BKT_SHIFT;  // 196 for n=100000

    char* ws = (char*)d_ws;
    size_t off = 0;
    auto alloc = [&](size_t bytes) -> void* {
        void* p = ws + off;
        off += (bytes + 255) & ~(size_t)255;
        return p;
    };
    unsigned short* hA  = (unsigned short*)alloc((size_t)n * 256 * 2);  // hs1
    unsigned short* hB  = (unsigned short*)alloc((size_t)n * 128 * 2);  // hs2
    unsigned short* W1T = (unsigned short*)alloc((size_t)256 * 512 * 2);
    unsigned short* W2T = (unsigned short*)alloc((size_t)128 * 256 * 2);
    int* deg     = (int*)alloc((size_t)n * 4);
    int* rowptr  = (int*)alloc(((size_t)n + 1) * 4);
    int* cursor  = (int*)alloc((size_t)n * 4);
    float* dinv  = (float*)alloc((size_t)n * 4);
    int* csr_src = (int*)alloc((size_t)E * 4);
    int* gcur    = (int*)alloc((size_t)nb * 4);
    size_t need_binned = off + (size_t)nb * BKT_CAP * 4 + 256;
    unsigned* binned = (unsigned*)alloc((size_t)nb * BKT_CAP * 4);

    if (need_binned <= ws_size && nb <= 256 && n < (1 << 23)) {
        hipMemsetAsync(gcur, 0, (size_t)nb * 4, stream);
        int ntiles = (E + BIN_TILE - 1) / BIN_TILE;
        bin_kernel<<<dim3(256), dim3(256), 0, stream>>>(eidx, E, nb, ntiles, gcur, binned);
        csr_build_kernel<<<dim3(nb), dim3(256), 0, stream>>>(binned, gcur, rowptr, dinv,
                                                             csr_src, nb, n);
    } else {
        hipMemsetAsync(deg, 0, (size_t)n * 4, stream);
        hist_kernel<<<dim3(1024), dim3(256), 0, stream>>>(eidx + E, E, deg);
        scan_kernel<<<dim3(1), dim3(256), 0, stream>>>(deg, rowptr, n);
        dinv_kernel<<<dim3((n + 255) / 256), dim3(256), 0, stream>>>(deg, dinv, n);
        hipMemcpyAsync(cursor, rowptr, (size_t)n * 4, hipMemcpyDeviceToDevice, stream);
        fill_kernel<<<dim3((E + 255) / 256), dim3(256), 0, stream>>>(eidx, E, cursor, csr_src);
    }

    // Weight prep (single launch)
    wt_kernel<<<dim3((512 * 256 + 256 * 128 + 255) / 256), dim3(256), 0, stream>>>(
        W1, W2, W1T, W2T);

    const int mblocks = (n + 63) / 64;

    // Layer 1 GEMM: hs1 = (x@W1)*dinv
    gemm_mfma<float, 4><<<dim3(mblocks), dim3(256), 0, stream>>>(
        x, W1T, dinv, hA, n, 256, 512);

    // Fused agg1 + gemm2: hs2 = (relu(agg(hs1))@W2)*dinv   (h1 stays in LDS)
    agg1_gemm2_kernel<<<dim3(mblocks), dim3(256), 0, stream>>>(
        hA, dinv, rowptr, csr_src, b1, W2T, hB, n);

    // agg2 + head fused
    agg2_head_kernel<<<dim3((n + 15) / 16), dim3(256), 0, stream>>>(
        hB, dinv, rowptr, csr_src, b2, Wl, bl, out, n);
}